// Round 6
// baseline (380.997 us; speedup 1.0000x reference)
//
#include <hip/hip_runtime.h>
#include <math.h>

// SSM_18597208391915: HiPPO-LegT recurrence, O(N) semiseparable solve.
// Ad = (I-cA)^{-1}(I+cA) = 2M - I  =>  h' = tanh(2*M(h + c*u*P) - h).
// Solve scan: T_{n+1} = alpha_n T_n + (P_n/d_n) w_n, y_n=(w_n - cP_n T_n)/d_n,
//   alpha_n = (1 - c*n)/(1 + c*(n+1))  (closed form, no sqrt).
// R6: SKEWED WAVE PIPELINE. A lower-triangular => low elements never depend
// on high ones. Hidden dim split over NW=4 waves; wave w at barrier-tick t
// computes step s = t-w, consuming wave-total affine-B values B_v[s] (v<w)
// published to LDS >=1 barrier earlier (race-free, prefetch-hidden).
// Per-wave issue ~1/4 of R5, 2-deep local chains, 2048 waves = 2/SIMD.
// All A-side (alpha-product) scan constants precomputed: per-lane aprod,
// DPP-level A's, per-lane cross-lane exclusive product Aexcl, inter-wave
// composition constants cin_v = prod of full-wave alpha-products Phi_z.

#define SEQ     784
#define OUT_DIM 10
#define NW      4    // waves per block
#define EPL     4    // elements per lane: NW*64*EPL = 1024 = HIDDEN

typedef float v2f __attribute__((ext_vector_type(2)));

#if __has_builtin(__builtin_elementwise_fma)
__device__ __forceinline__ v2f fma2(v2f a, v2f b, v2f c) {
    return __builtin_elementwise_fma(a, b, c);
}
#else
__device__ __forceinline__ v2f fma2(v2f a, v2f b, v2f c) {
    v2f r; r.x = fmaf(a.x, b.x, c.x); r.y = fmaf(a.y, b.y, c.y); return r;
}
#endif

#if __has_builtin(__builtin_amdgcn_exp2f)
#define EXP2F(x) __builtin_amdgcn_exp2f(x)
#else
#define EXP2F(x) __expf(0.69314718055994531f * (x))
#endif

// DPP move: result = src shuffled per CTRL; invalid/masked lanes get `old`.
template<int CTRL, int ROW_MASK>
__device__ __forceinline__ float dpp_mov(float src, float old) {
    return __int_as_float(__builtin_amdgcn_update_dpp(
        __float_as_int(old), __float_as_int(src), CTRL, ROW_MASK, 0xf, false));
}
// DPP ctrls: row_shr:N = 0x110|N, row_bcast15 = 0x142, row_bcast31 = 0x143,
//            wave_shr:1 = 0x138 (whole-wave shift down one lane)

__global__ __launch_bounds__(256, 1)
void ssm_hippo_scan(const float* __restrict__ x,     // (512, 784)
                    const float* __restrict__ C,     // (1024)
                    const float* __restrict__ W,     // (10)
                    const float* __restrict__ bvec,  // (10)
                    float* __restrict__ out)         // (512, 10)
{
    const int b    = blockIdx.x;
    const int tid  = threadIdx.x;
    const int wv   = tid >> 6;       // wave id 0..3 (owns elems [wv*256,..))
    const int lane = tid & 63;

    __shared__ float  u_s[SEQ + 1];
    __shared__ float4 tot_s[SEQ];    // tot_s[s] holds B_wave0..2 at step s
    __shared__ double part_s[NW];

    for (int t = tid; t < SEQ; t += 256) u_s[t] = x[b * SEQ + t];
    if (tid == 0) u_s[SEQ] = 0.0f;

    const double hdt  = 0.5 / (double)SEQ;             // c = dt/2
    const double L2E2 = 2.0 * 1.4426950408889634;      // 2*log2(e)

    // ---- per-element constants (n = (wv*64+lane)*EPL + i), fp64-derived
    v2f upc2[2], nhdtP2[2], pdin2[2], invd2v[2], aprod2[2];
    float alphas[EPL];
    double apd = 1.0;
#pragma unroll
    for (int i = 0; i < EPL; ++i) {
        const int    n = (wv * 64 + lane) * EPL + i;
        const double p = sqrt(1.0 + 2.0 * (double)n);
        const double d = 1.0 + hdt * (double)(n + 1);
        const double a = 1.0 - hdt * p * p / d;
        upc2[i>>1][i&1]   = (float)(L2E2 * hdt * p);
        nhdtP2[i>>1][i&1] = (float)(-hdt * p);
        pdin2[i>>1][i&1]  = (float)(p / d);
        invd2v[i>>1][i&1] = (float)(2.0 / d);
        aprod2[i>>1][i&1] = (float)apd;      // prod alpha_j, j<i within lane
        alphas[i]         = (float)a;
        apd *= a;
    }
    const float apH    = alphas[2] * alphas[3];
    const v2f   aprel2 = (v2f){1.0f, alphas[2]};

    // DPP-level A constants + per-lane exclusive cross-lane alpha product
    float Alev0, Alev1, Alev2, Alev3, Alev4, Alev5, Aexcl;
    {
        float A = (float)apd;
        Alev0 = A; A *= dpp_mov<0x111, 0xf>(A, 1.0f);
        Alev1 = A; A *= dpp_mov<0x112, 0xf>(A, 1.0f);
        Alev2 = A; A *= dpp_mov<0x114, 0xf>(A, 1.0f);
        Alev3 = A; A *= dpp_mov<0x118, 0xf>(A, 1.0f);
        Alev4 = A; A *= dpp_mov<0x142, 0xa>(A, 1.0f);
        Alev5 = A; A *= dpp_mov<0x143, 0xc>(A, 1.0f);
        Aexcl = dpp_mov<0x138, 0xf>(A, 1.0f);   // lane0 -> 1.0
    }

    // inter-wave composition constants: Tin(w) = sum_{v<w} cin_v * B_v[s],
    // cin_v = prod_{v<z<w} Phi_z;  Phi_z = prod(alpha_n, n in wave z)
    //       = prod(1 - c n) / prod(1 + c(n+1))   (no sqrt/div per n)
    float cin0 = 0.0f, cin1 = 0.0f, cin2 = 0.0f;
    {
        double n1 = 1.0, d1 = 1.0, n2 = 1.0, d2 = 1.0;
        for (int n = 256; n < 512; ++n) {
            n1 *= 1.0 - hdt * (double)n; d1 *= 1.0 + hdt * (double)(n + 1);
        }
        for (int n = 512; n < 768; ++n) {
            n2 *= 1.0 - hdt * (double)n; d2 *= 1.0 + hdt * (double)(n + 1);
        }
        const double Phi1 = n1 / d1, Phi2 = n2 / d2;
        if      (wv == 1) { cin0 = 1.0f; }
        else if (wv == 2) { cin1 = 1.0f; cin0 = (float)Phi1; }
        else if (wv == 3) { cin2 = 1.0f; cin1 = (float)Phi2;
                            cin0 = (float)(Phi1 * Phi2); }
    }

    const float c2  = (float)L2E2;           //  2*log2e
    const float nc4 = (float)(-2.0 * L2E2);  // -4*log2e

    // state Hs = 2*log2e * h
    v2f h2[2] = {(v2f){0.0f, 0.0f}, (v2f){0.0f, 0.0f}};

    __syncthreads();                         // u_s ready
    float u_cur = u_s[0];

#pragma unroll 1
    for (int t = 0; t < SEQ + NW - 1; ++t) {
        const int s = t - wv;                // this wave's time step
        if (0 <= s && s < SEQ) {
            // issue long-latency LDS reads first (consumed late in the step)
            const float  u_nx = u_s[s + 1];
            float4 Bt;
            if (wv > 0) Bt = tot_s[s];       // written >=1 barrier ago

            // ---- w = Hs + (2log2e c P) u ; gamma = (P/d) w
            const v2f uu = (v2f){u_cur, u_cur};
            v2f wv2[2], gam2[2], Tb2[2];
            wv2[0] = fma2(upc2[0], uu, h2[0]);  gam2[0] = pdin2[0] * wv2[0];
            wv2[1] = fma2(upc2[1], uu, h2[1]);  gam2[1] = pdin2[1] * wv2[1];

            // ---- local affine scan: two 2-deep chains + compose + fixup
            float Tl0 = gam2[0].x;                 // after elem0
            Tb2[0] = (v2f){0.0f, Tl0};             // Tloc[0]=0, Tloc[1]
            Tl0 = fmaf(alphas[1], Tl0, gam2[0].y); // low-half total
            float Tl1 = gam2[1].x;
            Tb2[1] = (v2f){0.0f, Tl1};
            Tl1 = fmaf(alphas[3], Tl1, gam2[1].y);
            Tb2[1] = fma2(aprel2, (v2f){Tl0, Tl0}, Tb2[1]); // hi fixup
            float B = fmaf(apH, Tl0, Tl1);         // lane affine-B total

            // ---- cross-lane affine scan (B chain, A's precomputed)
            float Bin;
            Bin = dpp_mov<0x111, 0xf>(B, 0.0f); B = fmaf(Alev0, Bin, B);
            Bin = dpp_mov<0x112, 0xf>(B, 0.0f); B = fmaf(Alev1, Bin, B);
            Bin = dpp_mov<0x114, 0xf>(B, 0.0f); B = fmaf(Alev2, Bin, B);
            Bin = dpp_mov<0x118, 0xf>(B, 0.0f); B = fmaf(Alev3, Bin, B);
            Bin = dpp_mov<0x142, 0xa>(B, 0.0f); B = fmaf(Alev4, Bin, B);
            Bin = dpp_mov<0x143, 0xc>(B, 0.0f); B = fmaf(Alev5, Bin, B);

            // publish this wave's total (inclusive B at lane 63)
            if (wv < NW - 1 && lane == 63) ((float*)&tot_s[s])[wv] = B;

            // ---- wave-exclusive start + incoming inter-wave composition
            const float Tst = dpp_mov<0x138, 0xf>(B, 0.0f);  // lane0 -> 0
            float Tin = 0.0f;
            if      (wv == 1) Tin = cin0 * Bt.x;
            else if (wv == 2) Tin = fmaf(cin0, Bt.x, cin1 * Bt.y);
            else if (wv == 3) Tin = fmaf(cin0, Bt.x,
                                    fmaf(cin1, Bt.y, cin2 * Bt.z));
            const float Tent = fmaf(Aexcl, Tin, Tst);
            const v2f  Tev  = (v2f){Tent, Tent};

            // ---- apply solve + Hs' = 2log2e*tanh(g)
#pragma unroll
            for (int j = 0; j < 2; ++j) {
                const v2f Tn  = fma2(aprod2[j], Tev, Tb2[j]);
                const v2f tmp = fma2(nhdtP2[j], Tn, wv2[j]);
                const v2f g2l = fma2(tmp, invd2v[j], -h2[j]);
                v2f e;
                e.x = EXP2F(g2l.x);
                e.y = EXP2F(g2l.y);
                const v2f ep = e + (v2f){1.0f, 1.0f};
                v2f r;
                r.x = __builtin_amdgcn_rcpf(ep.x);
                r.y = __builtin_amdgcn_rcpf(ep.y);
                h2[j] = fma2((v2f){nc4, nc4}, r, (v2f){c2, c2});
            }
            u_cur = u_nx;
        }
        __syncthreads();   // one barrier per tick; all comms cross >=1 tick
    }

    // ---- epilogue: tot = dot(h, C) over 1024; out = tot*W + b
    double acc = 0.0;
#pragma unroll
    for (int i = 0; i < EPL; ++i)
        acc = fma((double)C[(wv * 64 + lane) * EPL + i],
                  (double)h2[i>>1][i&1], acc);
#pragma unroll
    for (int off = 32; off > 0; off >>= 1)
        acc += __shfl_down(acc, off, 64);
    if (lane == 0) part_s[wv] = acc;
    __syncthreads();
    if (tid < OUT_DIM) {
        const double tot = (part_s[0] + part_s[1] + part_s[2] + part_s[3])
                           / (2.0 * 1.4426950408889634);
        out[b * OUT_DIM + tid] =
            (float)fma(tot, (double)W[tid], (double)bvec[tid]);
    }
}

extern "C" void kernel_launch(void* const* d_in, const int* in_sizes, int n_in,
                              void* d_out, int out_size, void* d_ws, size_t ws_size,
                              hipStream_t stream) {
    const float* x  = (const float*)d_in[0];   // (512, 784, 1)
    const float* C  = (const float*)d_in[1];   // (1, 1024)
    const float* W  = (const float*)d_in[2];   // (1, 10)
    const float* bv = (const float*)d_in[3];   // (10,)
    float* out      = (float*)d_out;           // (512, 10)
    hipLaunchKernelGGL(ssm_hippo_scan, dim3(512), dim3(256), 0, stream,
                       x, C, W, bv, out);
}

// Round 7
// 341.665 us; speedup vs baseline: 1.1151x; 1.1151x over previous
//
#include <hip/hip_runtime.h>
#include <math.h>

// SSM_18597208391915: HiPPO-LegT recurrence, O(N) semiseparable solve.
// Ad = (I-cA)^{-1}(I+cA) = 2M - I  =>  h' = tanh(2*M(h + c*u*P) - h).
// Solve scan: T_{n+1} = alpha_n T_n + (P_n/d_n) w_n, y_n=(w_n - cP_n T_n)/d_n.
// One wave per batch element (512 blocks x 64 lanes, 16 elems/lane); wall
// time = single-wave latency x 784 (1 wave/SIMD, nothing hides stalls).
// R6 post-mortem: skewed multi-wave pipeline LOST (barrier+LDS+shared issue
// port ate the issue reduction). R7: back to R5 single-wave structure, but
// PHASE-SEPARATED elementwise stages (all Tn, all tmp, all g2l, all exp2,
// all +1, all rcp, all h') so the 16 independent quarter-rate exp2/rcp
// pipeline at issue rate instead of serializing per group (~40cyc dep chain
// per v2f pair was ~400 cyc of exposed stall). Next step's w/gam fused into
// the tanh tail (w is elementwise in h) to shorten the inter-step path.

#define SEQ     784
#define OUT_DIM 10
#define EPL     16   // elements per lane: 64*16 = 1024 = HIDDEN
#define NG      (EPL/2)

typedef float v2f __attribute__((ext_vector_type(2)));

#if __has_builtin(__builtin_elementwise_fma)
__device__ __forceinline__ v2f fma2(v2f a, v2f b, v2f c) {
    return __builtin_elementwise_fma(a, b, c);
}
#else
__device__ __forceinline__ v2f fma2(v2f a, v2f b, v2f c) {
    v2f r; r.x = fmaf(a.x, b.x, c.x); r.y = fmaf(a.y, b.y, c.y); return r;
}
#endif

#if __has_builtin(__builtin_amdgcn_exp2f)
#define EXP2F(x) __builtin_amdgcn_exp2f(x)
#else
#define EXP2F(x) __expf(0.69314718055994531f * (x))
#endif

// DPP move: result = src shuffled per CTRL; invalid/masked lanes get `old`.
template<int CTRL, int ROW_MASK>
__device__ __forceinline__ float dpp_mov(float src, float old) {
    return __int_as_float(__builtin_amdgcn_update_dpp(
        __float_as_int(old), __float_as_int(src), CTRL, ROW_MASK, 0xf, false));
}
// DPP ctrls: row_shr:N = 0x110|N, row_bcast15 = 0x142, row_bcast31 = 0x143,
//            wave_shr:1 = 0x138 (whole-wave shift down one lane)

__global__ __launch_bounds__(64, 1)
void ssm_hippo_scan(const float* __restrict__ x,     // (512, 784)
                    const float* __restrict__ C,     // (1024)
                    const float* __restrict__ W,     // (10)
                    const float* __restrict__ bvec,  // (10)
                    float* __restrict__ out)         // (512, 10)
{
    const int b    = blockIdx.x;
    const int lane = threadIdx.x & 63;

    __shared__ float u_s[SEQ + 1];
    for (int t = lane; t < SEQ; t += 64) u_s[t] = x[b * SEQ + t];
    if (lane == 0) u_s[SEQ] = 0.0f;
    __syncthreads();

    const double hdt   = 0.5 / (double)SEQ;            // c = dt/2
    const double L2E2  = 2.0 * 1.4426950408889634;     // 2*log2(e)

    // ---- per-element constants (n = lane*EPL + i), derived in fp64
    v2f  upc2[NG];    // 2*log2e * c * P
    v2f  nhdtP2[NG];  // -c*P
    v2f  pdin2[NG];   // P/d
    v2f  invd2v[NG];  // 2/d
    v2f  aprod2[NG];  // prod_{j<i} alpha_j (within lane)
    v2f  aprel2[4];   // i>=8: aprod[i]/aprod[8]
    float alphas[EPL];
    float apH;        // prod alpha_{8..15}
    float Alev0, Alev1, Alev2, Alev3, Alev4, Alev5;
    {
        double apd = 1.0, ap8 = 1.0;
        double aprd[EPL];
#pragma unroll
        for (int i = 0; i < EPL; ++i) {
            const int    n = lane * EPL + i;
            const double p = sqrt(1.0 + 2.0 * (double)n);
            const double d = 1.0 + hdt * (double)(n + 1);
            const double a = 1.0 - hdt * p * p / d;
            upc2[i>>1][i&1]   = (float)(L2E2 * hdt * p);
            nhdtP2[i>>1][i&1] = (float)(-hdt * p);
            pdin2[i>>1][i&1]  = (float)(p / d);
            invd2v[i>>1][i&1] = (float)(2.0 / d);
            alphas[i]         = (float)a;
            aprd[i] = apd;
            aprod2[i>>1][i&1] = (float)apd;
            apd *= a;
            if (i == 8) ap8 = aprd[8];
        }
        apH = (float)(apd / ap8);
#pragma unroll
        for (int i = 8; i < EPL; ++i)
            aprel2[(i-8)>>1][i&1] = (float)(aprd[i] / ap8);
        float A = (float)apd;
        Alev0 = A; A *= dpp_mov<0x111, 0xf>(A, 1.0f);
        Alev1 = A; A *= dpp_mov<0x112, 0xf>(A, 1.0f);
        Alev2 = A; A *= dpp_mov<0x114, 0xf>(A, 1.0f);
        Alev3 = A; A *= dpp_mov<0x118, 0xf>(A, 1.0f);
        Alev4 = A; A *= dpp_mov<0x142, 0xa>(A, 1.0f);
        Alev5 = A;
    }

    const float c2  = (float)L2E2;          //  2*log2e
    const float nc4 = (float)(-2.0 * L2E2); // -4*log2e

    // state: Hs = 2*log2e*h, plus current-step w and gamma (sw-pipelined)
    v2f h2[NG], wv2[NG], gam2[NG];
    {
        const float u0 = u_s[0];
        const v2f  uu0 = (v2f){u0, u0};
#pragma unroll
        for (int j = 0; j < NG; ++j) {
            h2[j]   = (v2f){0.0f, 0.0f};
            wv2[j]  = upc2[j] * uu0;        // w for t=0 (h=0)
            gam2[j] = pdin2[j] * wv2[j];
        }
    }

#pragma unroll 1
    for (int t = 0; t < SEQ; ++t) {
        const float u_nx = u_s[t + 1];      // u for step t+1

        // ---- local affine scan over gam2: two 8-deep chains
        v2f Tb2[NG];
        float Tl0 = 0.0f, Tl1 = 0.0f;
#pragma unroll
        for (int i = 0; i < 8; ++i) {
            Tb2[i>>1][i&1] = Tl0;
            Tl0 = fmaf(alphas[i], Tl0, gam2[i>>1][i&1]);
        }
#pragma unroll
        for (int i = 8; i < EPL; ++i) {
            Tb2[i>>1][i&1] = Tl1;
            Tl1 = fmaf(alphas[i], Tl1, gam2[i>>1][i&1]);
        }
        const float Tl = fmaf(apH, Tl0, Tl1);   // lane affine-B total

        // ---- cross-lane affine scan, B chain only (A precomputed)
        float B = Tl;
        float Bin;
        Bin = dpp_mov<0x111, 0xf>(B, 0.0f); B = fmaf(Alev0, Bin, B);
        Bin = dpp_mov<0x112, 0xf>(B, 0.0f); B = fmaf(Alev1, Bin, B);
        // hi-half fixup overlaps DPP-chain latency:
        const v2f T8 = (v2f){Tl0, Tl0};
        Tb2[4] = fma2(aprel2[0], T8, Tb2[4]);
        Tb2[5] = fma2(aprel2[1], T8, Tb2[5]);
        Tb2[6] = fma2(aprel2[2], T8, Tb2[6]);
        Tb2[7] = fma2(aprel2[3], T8, Tb2[7]);
        Bin = dpp_mov<0x114, 0xf>(B, 0.0f); B = fmaf(Alev2, Bin, B);
        Bin = dpp_mov<0x118, 0xf>(B, 0.0f); B = fmaf(Alev3, Bin, B);
        Bin = dpp_mov<0x142, 0xa>(B, 0.0f); B = fmaf(Alev4, Bin, B);
        Bin = dpp_mov<0x143, 0xc>(B, 0.0f); B = fmaf(Alev5, Bin, B);
        const float Tstart = dpp_mov<0x138, 0xf>(B, 0.0f);  // excl; lane0=0
        const v2f Tst = (v2f){Tstart, Tstart};

        // ---- PHASE-SEPARATED elementwise stages (max ILP, min stall)
        v2f Tn[NG], tmp[NG], g2l[NG], e[NG], r[NG];
#pragma unroll
        for (int j = 0; j < NG; ++j) Tn[j]  = fma2(aprod2[j], Tst, Tb2[j]);
#pragma unroll
        for (int j = 0; j < NG; ++j) tmp[j] = fma2(nhdtP2[j], Tn[j], wv2[j]);
#pragma unroll
        for (int j = 0; j < NG; ++j) g2l[j] = fma2(tmp[j], invd2v[j], -h2[j]);
#pragma unroll
        for (int j = 0; j < NG; ++j) { e[j].x = EXP2F(g2l[j].x);
                                       e[j].y = EXP2F(g2l[j].y); }
#pragma unroll
        for (int j = 0; j < NG; ++j) e[j] = e[j] + (v2f){1.0f, 1.0f};
#pragma unroll
        for (int j = 0; j < NG; ++j) { r[j].x = __builtin_amdgcn_rcpf(e[j].x);
                                       r[j].y = __builtin_amdgcn_rcpf(e[j].y); }
        const v2f uu = (v2f){u_nx, u_nx};
#pragma unroll
        for (int j = 0; j < NG; ++j) {
            h2[j]   = fma2((v2f){nc4, nc4}, r[j], (v2f){c2, c2});
            wv2[j]  = fma2(upc2[j], uu, h2[j]);    // next step's w
            gam2[j] = pdin2[j] * wv2[j];           // next step's gamma
        }
    }

    // ---- epilogue (once): h = Hs/(2 log2e); out[b,o] = dot(h,C)*W[o]+b[o]
    double acc = 0.0;
#pragma unroll
    for (int i = 0; i < EPL; ++i)
        acc = fma((double)C[lane * EPL + i], (double)h2[i>>1][i&1], acc);
#pragma unroll
    for (int off = 32; off > 0; off >>= 1)
        acc += __shfl_down(acc, off, 64);
    const double tot = __shfl(acc, 0, 64) / (2.0 * 1.4426950408889634);
    if (lane < OUT_DIM)
        out[b * OUT_DIM + lane] = (float)fma(tot, (double)W[lane], (double)bvec[lane]);
}

extern "C" void kernel_launch(void* const* d_in, const int* in_sizes, int n_in,
                              void* d_out, int out_size, void* d_ws, size_t ws_size,
                              hipStream_t stream) {
    const float* x  = (const float*)d_in[0];   // (512, 784, 1)
    const float* C  = (const float*)d_in[1];   // (1, 1024)
    const float* W  = (const float*)d_in[2];   // (1, 10)
    const float* bv = (const float*)d_in[3];   // (10,)
    float* out      = (float*)d_out;           // (512, 10)
    hipLaunchKernelGGL(ssm_hippo_scan, dim3(512), dim3(64), 0, stream,
                       x, C, W, bv, out);
}